// Round 15
// baseline (86.037 us; speedup 1.0000x reference)
//
#include <hip/hip_runtime.h>

#define NQ 10
#define NG 4
#define QD 6
#define NBATCH 1024

// R19b: merged one-wave-per-circuit (R18-validated, absmax 0.0039) with the
// layer loop's LDS-pipe traffic ELIMINATED via builtin permlane swaps —
// now gated by __has_builtin so absence degrades to R18's validated path
// instead of a compile failure (de-risks the only novel construct).
// R18 post-mortem: VALUBusy 53%, qsim 41.3us; ~448 ds ops/wave (~17us LDS
// demand) SERIALIZED with ~22us VALU (4 waves/SIMD can't hide lgkmcnt).
// R15 PASSED on HW with raw-asm permlane swaps (same Givens math) at
// (256,2); R17's failure was the denser schedule/VGPR-cap interacting with
// compiler-invisible asm hazards -> builtin carrier is the safe vehicle.
//   xor1/xor2  = quad_perm fused v_fmac_dpp              [VALU DPP]
//   xor4/xor8  = row_half_mirror + fused mirror fmac     [VALU DPP, R15/16/18]
//   xor16/32   = permlane{16,32}_swap paired Givens       [VALU builtin]
//                (fallback: ds_swizzle 0x401F / shfl_xor  [LDS, R18])
// Expectation xor16/32: swapped-domain pair products x2 (R15-validated)
// on the builtin path; R18 cross_exp1 on the fallback.
// 4096 waves = 1024 blocks x 4; block = sample, wave = generator.
// Layout A: reg bits 0..3 <- amp bits 0..3, lane bits 0..5 <- amp 4..9.
// tan-form rotations + global scale (R9), CZ sign-bit xor layout-A masks.

#if defined(__has_builtin)
#if __has_builtin(__builtin_amdgcn_permlane16_swap) && \
    __has_builtin(__builtin_amdgcn_permlane32_swap)
#define HAVE_PLSWAP 1
#endif
#endif
#ifndef HAVE_PLSWAP
#define HAVE_PLSWAP 0
#endif

typedef unsigned u2v __attribute__((ext_vector_type(2)));

// ---------- DPP helpers ----------
template<int CTRL, int RM, int BM, bool BC>
__device__ __forceinline__ float dppmov(float x) {
    return __int_as_float(__builtin_amdgcn_update_dpp(
        0, __float_as_int(x), CTRL, RM, BM, BC));
}
template<int CTRL>
__device__ __forceinline__ float dpp1(float x) { return dppmov<CTRL,0xF,0xF,true>(x); }

template<int PAT>
__device__ __forceinline__ float swz(float x) {
    return __int_as_float(__builtin_amdgcn_ds_swizzle(__float_as_int(x), PAT));
}

// DPP ctrl: 0xB1 quad[1,0,3,2]=xor1, 0x4E quad[2,3,0,1]=xor2,
// 0x1B quad[3,2,1,0]=xor3, 0x141 row_half_mirror=xor7, 0x140 row_mirror=xor15.
struct FX1 { static __device__ __forceinline__ float f(float x){ return dpp1<0xB1>(x); } };
struct FX2 { static __device__ __forceinline__ float f(float x){ return dpp1<0x4E>(x); } };
struct FX4 { static __device__ __forceinline__ float f(float x){ return swz<0x101F>(x); } };
struct FX8 { static __device__ __forceinline__ float f(float x){ return swz<0x201F>(x); } };
struct FX16{ static __device__ __forceinline__ float f(float x){ return swz<0x401F>(x); } };
struct FX32{ static __device__ __forceinline__ float f(float x){ return __shfl_xor(x, 32, 64); } };

__device__ __forceinline__ float rlane(float v, int idx) {
    return __int_as_float(__builtin_amdgcn_readlane(__float_as_int(v), idx));
}

#if HAVE_PLSWAP
// gfx950 cross-row swaps via BUILTINS (compiler-visible, hazard-safe).
// Returns {new_vdst, new_vsrc}; fi=false, bound_ctrl=false = plain swap.
__device__ __forceinline__ void plswap16(float &a, float &b) {
    u2v r = __builtin_amdgcn_permlane16_swap(
        __float_as_uint(a), __float_as_uint(b), false, false);
    a = __uint_as_float(r[0]);
    b = __uint_as_float(r[1]);
}
__device__ __forceinline__ void plswap32(float &a, float &b) {
    u2v r = __builtin_amdgcn_permlane32_swap(
        __float_as_uint(a), __float_as_uint(b), false, false);
    a = __uint_as_float(r[0]);
    b = __uint_as_float(r[1]);
}
#endif

// wave-wide sum broadcast (validated R3..R18)
__device__ __forceinline__ float wave_reduce(float x) {
    x += dppmov<0x111,0xF,0xF,true >(x);
    x += dppmov<0x112,0xF,0xF,true >(x);
    x += dppmov<0x114,0xF,0xF,true >(x);
    x += dppmov<0x118,0xF,0xF,true >(x);
    x += dppmov<0x142,0xA,0xF,false>(x);
    x += dppmov<0x143,0xC,0xF,false>(x);
    return __int_as_float(__builtin_amdgcn_readlane(__float_as_int(x), 63));
}

// wave-wide product (R9-validated; once per wave)
__device__ __forceinline__ float wave_product(float x) {
    x *= dpp1<0xB1>(x);
    x *= dpp1<0x4E>(x);
    x *= FX4::f(x);
    x *= FX8::f(x);
    x *= FX16::f(x);
    x *= FX32::f(x);
    return x;
}

// (I - t*J) intra-register pair (R9-validated)
template<int M>
__device__ __forceinline__ void intra1(float (&s)[16], float t) {
#pragma unroll
    for (int j = 0; j < 16; ++j)
        if ((j & M) == 0) {
            const int k = j | M;
            float v0 = s[j], v1 = s[k];
            s[j] = fmaf(-t, v1, v0);
            s[k] = fmaf( t, v0, v1);
        }
}

// (I - t*J) cross-lane via fetch+fma (xor1/xor2 fused DPP; fallback xor16/32)
template<class PF, int LM>
__device__ __forceinline__ void cross1(float (&s)[16], float t, int lane) {
    const float sv = (lane & LM) ? t : -t;
#pragma unroll
    for (int j = 0; j < 16; ++j)
        s[j] = fmaf(PF::f(s[j]), sv, s[j]);
}

// (I - t*J) cross-lane via composed DPP: partner = s[lane ^ (X1^X2)]
// (R15/R16/R18-validated for xor4 = 3o7, xor8 = 15o7.)
template<int C1, int C2, int LM>
__device__ __forceinline__ void cross1_dpp2(float (&s)[16], float t, int lane) {
    const float sv = (lane & LM) ? t : -t;
#pragma unroll
    for (int j = 0; j < 16; ++j) {
        float tmp = dpp1<C1>(s[j]);
        s[j] = fmaf(dpp1<C2>(tmp), sv, s[j]);
    }
}

#if HAVE_PLSWAP
// (I - t*J) on lane-bit-4 / bit-5 via paired permlane swap Givens
// (R15-HW-validated math; builtin carrier).
__device__ __forceinline__ void cross_pl16(float (&s)[16], float t) {
#pragma unroll
    for (int j = 0; j < 16; j += 2) {
        float P = s[j], Q = s[j + 1];
        plswap16(P, Q);
        float Pn = fmaf(-t, Q, P);
        float Qn = fmaf( t, P, Q);
        plswap16(Pn, Qn);
        s[j] = Pn; s[j + 1] = Qn;
    }
}
__device__ __forceinline__ void cross_pl32(float (&s)[16], float t) {
#pragma unroll
    for (int j = 0; j < 16; j += 2) {
        float P = s[j], Q = s[j + 1];
        plswap32(P, Q);
        float Pn = fmaf(-t, Q, P);
        float Qn = fmaf( t, P, Q);
        plswap32(Pn, Qn);
        s[j] = Pn; s[j + 1] = Qn;
    }
}

// xor16 & xor32 expectation pair-sums in swapped domain (R15-HW-validated:
// one pass covers BOTH regs of each pair; full sum = 2x pair sum). Copies.
__device__ __forceinline__ void exp_pl(const float (&s)[16], float &p16, float &p32) {
#pragma unroll
    for (int j = 0; j < 16; j += 2) {
        float P = s[j], Q = s[j + 1];
        plswap16(P, Q);
        p16 = fmaf(P, Q, p16);
        plswap32(P, Q);
        p32 = fmaf(P, Q, p32);
    }
}
#endif

template<class PF>
__device__ __forceinline__ float cross_exp1(const float (&s)[16]) {
    float a = 0.f;
#pragma unroll
    for (int j = 0; j < 16; ++j)
        a = fmaf(PF::f(s[j]), s[j], a);
    return a;
}

// expectation with composed-DPP partner (xor4/xor8). (R15..R18-validated)
template<int C1, int C2>
__device__ __forceinline__ float cross_exp_dpp2(const float (&s)[16]) {
    float a = 0.f;
#pragma unroll
    for (int j = 0; j < 16; ++j) {
        float tmp = dpp1<C1>(s[j]);
        a = fmaf(dpp1<C2>(tmp), s[j], a);
    }
    return a;
}

template<int M>
__device__ __forceinline__ float intra_exp1(const float (&s)[16]) {
    float a = 0.f;
#pragma unroll
    for (int j = 0; j < 16; ++j)
        a += s[j] * s[j ^ M];
    return a;
}

__global__ __launch_bounds__(256, 2) void qsim_kernel(
    const float* __restrict__ noise,     // (NBATCH, NQ)
    const float* __restrict__ qp,        // (NG, QD, NQ)
    float* __restrict__ out)             // (NBATCH, NG*NQ)
{
    const int wave = threadIdx.x >> 6;
    const int lane = threadIdx.x & 63;
    const int cid  = blockIdx.x * 4 + wave;   // 4096 circuits = 1024 b x 4 g
    const int g    = cid & 3;                 // = wave (wave-uniform)
    const int b    = cid >> 2;                // = blockIdx.x (shared in block)

    // ---- weights: lane-parallel sincos once; t = tan, scale2 = prod(c)^2 ----
    float wt, scale2;
    {
        const int widx = (lane < QD * NQ) ? lane : 0;
        float sv, cv;
        __sincosf(0.5f * qp[g * (QD * NQ) + widx], &sv, &cv);
        wt = sv / cv;
        float cvc = (lane < QD * NQ) ? cv : 1.0f;
        float p = wave_product(cvc);
        scale2 = p * p;
    }

    // ---- init: complex product state, ONCE per circuit, both comps in regs ----
    float sre[16], sim[16];
    {
        float nc[NQ], ns[NQ];
#pragma unroll
        for (int q = 0; q < NQ; ++q)
            __sincosf(0.5f * noise[b * NQ + q], &ns[q], &nc[q]);

        auto facr = [&](int q, int bit) { return bit ? nc[q]*ns[q] : nc[q]*nc[q]; };
        auto faci = [&](int q, int bit) { return bit ? -nc[q]*ns[q] : -ns[q]*ns[q]; };

        float hr = 1.f, hi = 0.f;
#pragma unroll
        for (int p = 4; p <= 9; ++p) {
            const int q = NQ - 1 - p, bit = (lane >> (p - 4)) & 1;
            float fr = facr(q, bit), fi = faci(q, bit);
            float tr = hr * fr - hi * fi;
            float ti = hr * fi + hi * fr;
            hr = tr; hi = ti;
        }
        float t01r[4], t01i[4], t23r[4], t23i[4];
#pragma unroll
        for (int a = 0; a < 4; ++a) {
            float f9r = facr(9, a & 1), f9i = faci(9, a & 1);
            float f8r = facr(8, (a >> 1) & 1), f8i = faci(8, (a >> 1) & 1);
            t01r[a] = f9r * f8r - f9i * f8i;
            t01i[a] = f9r * f8i + f9i * f8r;
            float f7r = facr(7, a & 1), f7i = faci(7, a & 1);
            float f6r = facr(6, (a >> 1) & 1), f6i = faci(6, (a >> 1) & 1);
            t23r[a] = f7r * f6r - f7i * f6i;
            t23i[a] = f7r * f6i + f7i * f6r;
        }
        float prer[4], prei[4];
#pragma unroll
        for (int a = 0; a < 4; ++a) {
            prer[a] = hr * t01r[a] - hi * t01i[a];
            prei[a] = hr * t01i[a] + hi * t01r[a];
        }
#pragma unroll
        for (int j = 0; j < 16; ++j) {
            sre[j] = prer[j & 3] * t23r[j >> 2] - prei[j & 3] * t23i[j >> 2];
            sim[j] = prer[j & 3] * t23i[j >> 2] + prei[j & 3] * t23r[j >> 2];
        }
    }

    // ---- CZ sign masks, layout A (R9/R12-validated parity decomposition) ----
    unsigned aE, aO;
    {
        unsigned parA = (unsigned)(__popc(lane & (lane >> 1)) & 1) << 31;
        aE = parA;                                     // j < 8
        aO = parA ^ ((unsigned)(lane & 1) << 31);      // j >= 8 (pair j3,l0)
    }
    auto czA = [&](float (&v)[16]) {
#pragma unroll
        for (int j = 0; j < 16; ++j) {
            const bool jp = (__popc(j & (j >> 1)) & 1) != 0;         // compile-time
            const unsigned base = (j & 8) ? aO : aE;
            const unsigned m = jp ? (base ^ 0x80000000u) : base;
            v[j] = __uint_as_float(__float_as_uint(v[j]) ^ m);
        }
    };

    // ---- QD layers: sre/sim interleaved = two independent dep chains. RY on
    // distinct wires commute exactly, so order is free. ----
#pragma unroll 1
    for (int l = 0; l < QD; ++l) {
        float t[NQ];
#pragma unroll
        for (int q = 0; q < NQ; ++q) t[q] = rlane(wt, l * NQ + q);

#if HAVE_PLSWAP
        cross_pl32(sre, t[0]);                       // wire 0 (lane bit 5) [VALU]
        cross_pl32(sim, t[0]);
        cross_pl16(sre, t[1]);                       // wire 1 (lane bit 4) [VALU]
        cross_pl16(sim, t[1]);
#else
        cross1<FX32,32>(sre, t[0], lane);            // wire 0 [LDS fallback]
        cross1<FX32,32>(sim, t[0], lane);
        cross1<FX16,16>(sre, t[1], lane);            // wire 1 [LDS fallback]
        cross1<FX16,16>(sim, t[1], lane);
#endif
        cross1_dpp2<0x141,0x140, 8>(sre, t[2], lane); // wire 2 (xor8) [DPP]
        cross1_dpp2<0x141,0x140, 8>(sim, t[2], lane);
        cross1_dpp2<0x141,0x1B,  4>(sre, t[3], lane); // wire 3 (xor4) [DPP]
        cross1_dpp2<0x141,0x1B,  4>(sim, t[3], lane);
        intra1<1>(sre, t[9]);  intra1<1>(sim, t[9]); // wires 9..6 (reg bits)
        intra1<2>(sre, t[8]);  intra1<2>(sim, t[8]);
        intra1<4>(sre, t[7]);  intra1<4>(sim, t[7]);
        intra1<8>(sre, t[6]);  intra1<8>(sim, t[6]);
        cross1<FX1, 1>(sre, t[5], lane);             // wire 5 (lane bit 0) [DPP]
        cross1<FX1, 1>(sim, t[5], lane);
        cross1<FX2, 2>(sre, t[4], lane);             // wire 4 (lane bit 1) [DPP]
        cross1<FX2, 2>(sim, t[4], lane);
        czA(sre); czA(sim);
    }

    // ---- expectations: a_q = sum(re*re_partner) + sum(im*im_partner)
    // (merged accumulator -> ONE reduce per wire). ----
    float myp = 0.f;
    {
#if HAVE_PLSWAP
        float p16 = 0.f, p32 = 0.f;
        exp_pl(sre, p16, p32);
        exp_pl(sim, p16, p32);
        float a0 = 2.0f * p32;
        float a1 = 2.0f * p16;
#else
        float a0 = cross_exp1<FX32>(sre) + cross_exp1<FX32>(sim);
        float a1 = cross_exp1<FX16>(sre) + cross_exp1<FX16>(sim);
#endif
        float a2 = cross_exp_dpp2<0x141,0x140>(sre) + cross_exp_dpp2<0x141,0x140>(sim);
        float a3 = cross_exp_dpp2<0x141,0x1B >(sre) + cross_exp_dpp2<0x141,0x1B >(sim);
        float a4 = cross_exp1<FX2>(sre) + cross_exp1<FX2>(sim);
        float a5 = cross_exp1<FX1>(sre) + cross_exp1<FX1>(sim);
        float a6 = intra_exp1<8>(sre) + intra_exp1<8>(sim);
        float a7 = intra_exp1<4>(sre) + intra_exp1<4>(sim);
        float a8 = intra_exp1<2>(sre) + intra_exp1<2>(sim);
        float a9 = intra_exp1<1>(sre) + intra_exp1<1>(sim);
        float e0 = wave_reduce(a0);
        float e1 = wave_reduce(a1);
        float e2 = wave_reduce(a2);
        float e3 = wave_reduce(a3);
        float e4 = wave_reduce(a4);
        float e5 = wave_reduce(a5);
        float e6 = wave_reduce(a6);
        float e7 = wave_reduce(a7);
        float e8 = wave_reduce(a8);
        float e9 = wave_reduce(a9);
        myp = (lane == 0) ? e0 : myp;
        myp = (lane == 1) ? e1 : myp;
        myp = (lane == 2) ? e2 : myp;
        myp = (lane == 3) ? e3 : myp;
        myp = (lane == 4) ? e4 : myp;
        myp = (lane == 5) ? e5 : myp;
        myp = (lane == 6) ? e6 : myp;
        myp = (lane == 7) ? e7 : myp;
        myp = (lane == 8) ? e8 : myp;
        myp = (lane == 9) ? e9 : myp;
    }

    // ---- store: one wave owns the full (b,g) output row; no LDS/barrier ----
    if (lane < NQ)
        out[b * (NG * NQ) + g * NQ + lane] = myp * scale2;
}

extern "C" void kernel_launch(void* const* d_in, const int* in_sizes, int n_in,
                              void* d_out, int out_size, void* d_ws, size_t ws_size,
                              hipStream_t stream) {
    const float* noise = (const float*)d_in[0];   // (1024, 10) float32
    const float* qp    = (const float*)d_in[1];   // (4, 6, 10) float32
    float* out = (float*)d_out;                   // (1024, 40) float32

    const int nblocks = NBATCH;                   // 1024 blocks x 4 waves
    qsim_kernel<<<nblocks, 256, 0, stream>>>(noise, qp, out);
}

// Round 16
// 84.666 us; speedup vs baseline: 1.0162x; 1.0162x over previous
//
#include <hip/hip_runtime.h>

#define NQ 10
#define NG 4
#define QD 6
#define NBATCH 1024

// R20: merged one-wave-per-circuit, DUAL-PIPE split — exactly one delta from
// R19b (passed): sre's xor16/32 back on the LDS pipe (R18-validated path in
// THIS structure), sim's xor16/32 stays on R19b's builtin permlane (also
// validated in this structure). Post-mortems: all-LDS merged (R18) = 41.3us
// (VALUBusy 53%, pipes serialized); all-VALU merged (R19b) = ~38us (cross-
// lane VALU ops ~2x plain issue cost). Each pipe alone is near-capacity ->
// feed both concurrently from within each wave; LDS wires issue FIRST per
// layer so lgkmcnt hides under sim's permlane/DPP work.
//   sre xor16/32 = ds_swizzle 0x401F / shfl_xor        [LDS pipe, R18]
//   sim xor16/32 = permlane{16,32}_swap paired Givens   [VALU builtin, R19b]
//   xor4/xor8    = row_half_mirror + fused mirror fmac  [VALU DPP]
//   xor1/xor2    = quad_perm fused v_fmac_dpp           [VALU DPP]
// Expectations: sre xor16/32 via cross_exp1 (LDS), sim via swapped-domain
// pair products x2 (R15/R19b-validated). Merged accumulators, 10 reduces.
// Fallback (no permlane builtins): both comps LDS = exact R18 (passed).
// 4096 waves = 1024 blocks x 4; block = sample, wave = generator.
// Layout A: reg bits 0..3 <- amp bits 0..3, lane bits 0..5 <- amp 4..9.
// tan-form rotations + global scale (R9), CZ sign-bit xor layout-A masks.
// DECISION RULE: if qsim >= 36us, pipe assignment can't move the floor ->
// next structure: 32-reg duplexed-comp layout (re=lanes 0-31, im=32-63).

#if defined(__has_builtin)
#if __has_builtin(__builtin_amdgcn_permlane16_swap) && \
    __has_builtin(__builtin_amdgcn_permlane32_swap)
#define HAVE_PLSWAP 1
#endif
#endif
#ifndef HAVE_PLSWAP
#define HAVE_PLSWAP 0
#endif

typedef unsigned u2v __attribute__((ext_vector_type(2)));

// ---------- DPP helpers ----------
template<int CTRL, int RM, int BM, bool BC>
__device__ __forceinline__ float dppmov(float x) {
    return __int_as_float(__builtin_amdgcn_update_dpp(
        0, __float_as_int(x), CTRL, RM, BM, BC));
}
template<int CTRL>
__device__ __forceinline__ float dpp1(float x) { return dppmov<CTRL,0xF,0xF,true>(x); }

template<int PAT>
__device__ __forceinline__ float swz(float x) {
    return __int_as_float(__builtin_amdgcn_ds_swizzle(__float_as_int(x), PAT));
}

// DPP ctrl: 0xB1 quad[1,0,3,2]=xor1, 0x4E quad[2,3,0,1]=xor2,
// 0x1B quad[3,2,1,0]=xor3, 0x141 row_half_mirror=xor7, 0x140 row_mirror=xor15.
struct FX1 { static __device__ __forceinline__ float f(float x){ return dpp1<0xB1>(x); } };
struct FX2 { static __device__ __forceinline__ float f(float x){ return dpp1<0x4E>(x); } };
struct FX4 { static __device__ __forceinline__ float f(float x){ return swz<0x101F>(x); } };
struct FX8 { static __device__ __forceinline__ float f(float x){ return swz<0x201F>(x); } };
struct FX16{ static __device__ __forceinline__ float f(float x){ return swz<0x401F>(x); } };
struct FX32{ static __device__ __forceinline__ float f(float x){ return __shfl_xor(x, 32, 64); } };

__device__ __forceinline__ float rlane(float v, int idx) {
    return __int_as_float(__builtin_amdgcn_readlane(__float_as_int(v), idx));
}

#if HAVE_PLSWAP
// gfx950 cross-row swaps via BUILTINS (compiler-visible, hazard-safe).
// Returns {new_vdst, new_vsrc}; fi=false, bound_ctrl=false = plain swap.
__device__ __forceinline__ void plswap16(float &a, float &b) {
    u2v r = __builtin_amdgcn_permlane16_swap(
        __float_as_uint(a), __float_as_uint(b), false, false);
    a = __uint_as_float(r[0]);
    b = __uint_as_float(r[1]);
}
__device__ __forceinline__ void plswap32(float &a, float &b) {
    u2v r = __builtin_amdgcn_permlane32_swap(
        __float_as_uint(a), __float_as_uint(b), false, false);
    a = __uint_as_float(r[0]);
    b = __uint_as_float(r[1]);
}
#endif

// wave-wide sum broadcast (validated R3..R19b)
__device__ __forceinline__ float wave_reduce(float x) {
    x += dppmov<0x111,0xF,0xF,true >(x);
    x += dppmov<0x112,0xF,0xF,true >(x);
    x += dppmov<0x114,0xF,0xF,true >(x);
    x += dppmov<0x118,0xF,0xF,true >(x);
    x += dppmov<0x142,0xA,0xF,false>(x);
    x += dppmov<0x143,0xC,0xF,false>(x);
    return __int_as_float(__builtin_amdgcn_readlane(__float_as_int(x), 63));
}

// wave-wide product (R9-validated; once per wave)
__device__ __forceinline__ float wave_product(float x) {
    x *= dpp1<0xB1>(x);
    x *= dpp1<0x4E>(x);
    x *= FX4::f(x);
    x *= FX8::f(x);
    x *= FX16::f(x);
    x *= FX32::f(x);
    return x;
}

// (I - t*J) intra-register pair (R9-validated)
template<int M>
__device__ __forceinline__ void intra1(float (&s)[16], float t) {
#pragma unroll
    for (int j = 0; j < 16; ++j)
        if ((j & M) == 0) {
            const int k = j | M;
            float v0 = s[j], v1 = s[k];
            s[j] = fmaf(-t, v1, v0);
            s[k] = fmaf( t, v0, v1);
        }
}

// (I - t*J) cross-lane via fetch+fma (xor1/xor2 fused DPP; sre xor16/32 LDS)
template<class PF, int LM>
__device__ __forceinline__ void cross1(float (&s)[16], float t, int lane) {
    const float sv = (lane & LM) ? t : -t;
#pragma unroll
    for (int j = 0; j < 16; ++j)
        s[j] = fmaf(PF::f(s[j]), sv, s[j]);
}

// (I - t*J) cross-lane via composed DPP: partner = s[lane ^ (X1^X2)]
// (R15..R19b-validated for xor4 = 3o7, xor8 = 15o7.)
template<int C1, int C2, int LM>
__device__ __forceinline__ void cross1_dpp2(float (&s)[16], float t, int lane) {
    const float sv = (lane & LM) ? t : -t;
#pragma unroll
    for (int j = 0; j < 16; ++j) {
        float tmp = dpp1<C1>(s[j]);
        s[j] = fmaf(dpp1<C2>(tmp), sv, s[j]);
    }
}

#if HAVE_PLSWAP
// (I - t*J) on lane-bit-4 / bit-5 via paired permlane swap Givens
// (R15-HW + R19b-validated; builtin carrier).
__device__ __forceinline__ void cross_pl16(float (&s)[16], float t) {
#pragma unroll
    for (int j = 0; j < 16; j += 2) {
        float P = s[j], Q = s[j + 1];
        plswap16(P, Q);
        float Pn = fmaf(-t, Q, P);
        float Qn = fmaf( t, P, Q);
        plswap16(Pn, Qn);
        s[j] = Pn; s[j + 1] = Qn;
    }
}
__device__ __forceinline__ void cross_pl32(float (&s)[16], float t) {
#pragma unroll
    for (int j = 0; j < 16; j += 2) {
        float P = s[j], Q = s[j + 1];
        plswap32(P, Q);
        float Pn = fmaf(-t, Q, P);
        float Qn = fmaf( t, P, Q);
        plswap32(Pn, Qn);
        s[j] = Pn; s[j + 1] = Qn;
    }
}

// xor16 & xor32 expectation pair-sums in swapped domain (R19b-validated:
// one pass covers BOTH regs of each pair; full sum = 2x pair sum). Copies.
__device__ __forceinline__ void exp_pl(const float (&s)[16], float &p16, float &p32) {
#pragma unroll
    for (int j = 0; j < 16; j += 2) {
        float P = s[j], Q = s[j + 1];
        plswap16(P, Q);
        p16 = fmaf(P, Q, p16);
        plswap32(P, Q);
        p32 = fmaf(P, Q, p32);
    }
}
#endif

template<class PF>
__device__ __forceinline__ float cross_exp1(const float (&s)[16]) {
    float a = 0.f;
#pragma unroll
    for (int j = 0; j < 16; ++j)
        a = fmaf(PF::f(s[j]), s[j], a);
    return a;
}

// expectation with composed-DPP partner (xor4/xor8). (R15..R19b-validated)
template<int C1, int C2>
__device__ __forceinline__ float cross_exp_dpp2(const float (&s)[16]) {
    float a = 0.f;
#pragma unroll
    for (int j = 0; j < 16; ++j) {
        float tmp = dpp1<C1>(s[j]);
        a = fmaf(dpp1<C2>(tmp), s[j], a);
    }
    return a;
}

template<int M>
__device__ __forceinline__ float intra_exp1(const float (&s)[16]) {
    float a = 0.f;
#pragma unroll
    for (int j = 0; j < 16; ++j)
        a += s[j] * s[j ^ M];
    return a;
}

__global__ __launch_bounds__(256, 2) void qsim_kernel(
    const float* __restrict__ noise,     // (NBATCH, NQ)
    const float* __restrict__ qp,        // (NG, QD, NQ)
    float* __restrict__ out)             // (NBATCH, NG*NQ)
{
    const int wave = threadIdx.x >> 6;
    const int lane = threadIdx.x & 63;
    const int cid  = blockIdx.x * 4 + wave;   // 4096 circuits = 1024 b x 4 g
    const int g    = cid & 3;                 // = wave (wave-uniform)
    const int b    = cid >> 2;                // = blockIdx.x (shared in block)

    // ---- weights: lane-parallel sincos once; t = tan, scale2 = prod(c)^2 ----
    float wt, scale2;
    {
        const int widx = (lane < QD * NQ) ? lane : 0;
        float sv, cv;
        __sincosf(0.5f * qp[g * (QD * NQ) + widx], &sv, &cv);
        wt = sv / cv;
        float cvc = (lane < QD * NQ) ? cv : 1.0f;
        float p = wave_product(cvc);
        scale2 = p * p;
    }

    // ---- init: complex product state, ONCE per circuit, both comps in regs ----
    float sre[16], sim[16];
    {
        float nc[NQ], ns[NQ];
#pragma unroll
        for (int q = 0; q < NQ; ++q)
            __sincosf(0.5f * noise[b * NQ + q], &ns[q], &nc[q]);

        auto facr = [&](int q, int bit) { return bit ? nc[q]*ns[q] : nc[q]*nc[q]; };
        auto faci = [&](int q, int bit) { return bit ? -nc[q]*ns[q] : -ns[q]*ns[q]; };

        float hr = 1.f, hi = 0.f;
#pragma unroll
        for (int p = 4; p <= 9; ++p) {
            const int q = NQ - 1 - p, bit = (lane >> (p - 4)) & 1;
            float fr = facr(q, bit), fi = faci(q, bit);
            float tr = hr * fr - hi * fi;
            float ti = hr * fi + hi * fr;
            hr = tr; hi = ti;
        }
        float t01r[4], t01i[4], t23r[4], t23i[4];
#pragma unroll
        for (int a = 0; a < 4; ++a) {
            float f9r = facr(9, a & 1), f9i = faci(9, a & 1);
            float f8r = facr(8, (a >> 1) & 1), f8i = faci(8, (a >> 1) & 1);
            t01r[a] = f9r * f8r - f9i * f8i;
            t01i[a] = f9r * f8i + f9i * f8r;
            float f7r = facr(7, a & 1), f7i = faci(7, a & 1);
            float f6r = facr(6, (a >> 1) & 1), f6i = faci(6, (a >> 1) & 1);
            t23r[a] = f7r * f6r - f7i * f6i;
            t23i[a] = f7r * f6i + f7i * f6r;
        }
        float prer[4], prei[4];
#pragma unroll
        for (int a = 0; a < 4; ++a) {
            prer[a] = hr * t01r[a] - hi * t01i[a];
            prei[a] = hr * t01i[a] + hi * t01r[a];
        }
#pragma unroll
        for (int j = 0; j < 16; ++j) {
            sre[j] = prer[j & 3] * t23r[j >> 2] - prei[j & 3] * t23i[j >> 2];
            sim[j] = prer[j & 3] * t23i[j >> 2] + prei[j & 3] * t23r[j >> 2];
        }
    }

    // ---- CZ sign masks, layout A (R9/R12-validated parity decomposition) ----
    unsigned aE, aO;
    {
        unsigned parA = (unsigned)(__popc(lane & (lane >> 1)) & 1) << 31;
        aE = parA;                                     // j < 8
        aO = parA ^ ((unsigned)(lane & 1) << 31);      // j >= 8 (pair j3,l0)
    }
    auto czA = [&](float (&v)[16]) {
#pragma unroll
        for (int j = 0; j < 16; ++j) {
            const bool jp = (__popc(j & (j >> 1)) & 1) != 0;         // compile-time
            const unsigned base = (j & 8) ? aO : aE;
            const unsigned m = jp ? (base ^ 0x80000000u) : base;
            v[j] = __uint_as_float(__float_as_uint(v[j]) ^ m);
        }
    };

    // ---- QD layers: sre's xor16/32 on LDS pipe issued FIRST (latency hides
    // under sim's permlane/DPP VALU work); two independent dep chains. RY on
    // distinct wires commute exactly, so order is free. ----
#pragma unroll 1
    for (int l = 0; l < QD; ++l) {
        float t[NQ];
#pragma unroll
        for (int q = 0; q < NQ; ++q) t[q] = rlane(wt, l * NQ + q);

#if HAVE_PLSWAP
        cross1<FX32,32>(sre, t[0], lane);            // sre wire 0 [LDS, issue early]
        cross1<FX16,16>(sre, t[1], lane);            // sre wire 1 [LDS]
        cross_pl32(sim, t[0]);                       // sim wire 0 [VALU permlane]
        cross_pl16(sim, t[1]);                       // sim wire 1 [VALU permlane]
#else
        cross1<FX32,32>(sre, t[0], lane);            // fallback: both LDS (=R18)
        cross1<FX32,32>(sim, t[0], lane);
        cross1<FX16,16>(sre, t[1], lane);
        cross1<FX16,16>(sim, t[1], lane);
#endif
        cross1_dpp2<0x141,0x140, 8>(sim, t[2], lane); // wire 2 (xor8) [DPP] - sim
        cross1_dpp2<0x141,0x140, 8>(sre, t[2], lane); //   first (sre LDS in flight)
        cross1_dpp2<0x141,0x1B,  4>(sim, t[3], lane); // wire 3 (xor4) [DPP]
        cross1_dpp2<0x141,0x1B,  4>(sre, t[3], lane);
        intra1<1>(sim, t[9]);  intra1<1>(sre, t[9]); // wires 9..6 (reg bits)
        intra1<2>(sim, t[8]);  intra1<2>(sre, t[8]);
        intra1<4>(sim, t[7]);  intra1<4>(sre, t[7]);
        intra1<8>(sim, t[6]);  intra1<8>(sre, t[6]);
        cross1<FX1, 1>(sim, t[5], lane);             // wire 5 (lane bit 0) [DPP]
        cross1<FX1, 1>(sre, t[5], lane);
        cross1<FX2, 2>(sim, t[4], lane);             // wire 4 (lane bit 1) [DPP]
        cross1<FX2, 2>(sre, t[4], lane);
        czA(sre); czA(sim);
    }

    // ---- expectations: a_q = sum(re*re_partner) + sum(im*im_partner)
    // (merged accumulator -> ONE reduce per wire; sre LDS fetches first). ----
    float myp = 0.f;
    {
#if HAVE_PLSWAP
        float a0 = cross_exp1<FX32>(sre);            // [LDS, issue early]
        float a1 = cross_exp1<FX16>(sre);            // [LDS]
        float p16 = 0.f, p32 = 0.f;
        exp_pl(sim, p16, p32);                       // [VALU permlane]
        a0 = fmaf(2.0f, p32, a0);
        a1 = fmaf(2.0f, p16, a1);
#else
        float a0 = cross_exp1<FX32>(sre) + cross_exp1<FX32>(sim);
        float a1 = cross_exp1<FX16>(sre) + cross_exp1<FX16>(sim);
#endif
        float a2 = cross_exp_dpp2<0x141,0x140>(sre) + cross_exp_dpp2<0x141,0x140>(sim);
        float a3 = cross_exp_dpp2<0x141,0x1B >(sre) + cross_exp_dpp2<0x141,0x1B >(sim);
        float a4 = cross_exp1<FX2>(sre) + cross_exp1<FX2>(sim);
        float a5 = cross_exp1<FX1>(sre) + cross_exp1<FX1>(sim);
        float a6 = intra_exp1<8>(sre) + intra_exp1<8>(sim);
        float a7 = intra_exp1<4>(sre) + intra_exp1<4>(sim);
        float a8 = intra_exp1<2>(sre) + intra_exp1<2>(sim);
        float a9 = intra_exp1<1>(sre) + intra_exp1<1>(sim);
        float e0 = wave_reduce(a0);
        float e1 = wave_reduce(a1);
        float e2 = wave_reduce(a2);
        float e3 = wave_reduce(a3);
        float e4 = wave_reduce(a4);
        float e5 = wave_reduce(a5);
        float e6 = wave_reduce(a6);
        float e7 = wave_reduce(a7);
        float e8 = wave_reduce(a8);
        float e9 = wave_reduce(a9);
        myp = (lane == 0) ? e0 : myp;
        myp = (lane == 1) ? e1 : myp;
        myp = (lane == 2) ? e2 : myp;
        myp = (lane == 3) ? e3 : myp;
        myp = (lane == 4) ? e4 : myp;
        myp = (lane == 5) ? e5 : myp;
        myp = (lane == 6) ? e6 : myp;
        myp = (lane == 7) ? e7 : myp;
        myp = (lane == 8) ? e8 : myp;
        myp = (lane == 9) ? e9 : myp;
    }

    // ---- store: one wave owns the full (b,g) output row; no LDS/barrier ----
    if (lane < NQ)
        out[b * (NG * NQ) + g * NQ + lane] = myp * scale2;
}

extern "C" void kernel_launch(void* const* d_in, const int* in_sizes, int n_in,
                              void* d_out, int out_size, void* d_ws, size_t ws_size,
                              hipStream_t stream) {
    const float* noise = (const float*)d_in[0];   // (1024, 10) float32
    const float* qp    = (const float*)d_in[1];   // (4, 6, 10) float32
    float* out = (float*)d_out;                   // (1024, 40) float32

    const int nblocks = NBATCH;                   // 1024 blocks x 4 waves
    qsim_kernel<<<nblocks, 256, 0, stream>>>(noise, qp, out);
}